// Round 16
// baseline (6969.998 us; speedup 1.0000x reference)
//
#include <hip/hip_runtime.h>
#include <math.h>

#define B_SZ   32
#define T_SZ   1024
#define IN_SZ  512
#define SEN    512
#define HID    1024
#define MOT    512
#define OUT_SZ 512

#define NBLK   32          // scan blocks (j-slices)
#define JSL    32          // j's per block
#define K2     512         // f16-pair dwords per h row
#define WPAD   516         // padded w_lds row stride (dwords)
#define PARSZ  16384       // u64 words per hx parity: 128 chunks x 32 b x 4

typedef __fp16  f16x8 __attribute__((ext_vector_type(8)));
typedef float   f32x4 __attribute__((ext_vector_type(4)));

__device__ inline uint32_t pk16(float a, float b) {
  auto p = __builtin_amdgcn_cvt_pkrtz(a, b);
  return __builtin_bit_cast(uint32_t, p);
}

// ---------------------------------------------------------------------------
// f32 tile GEMM (K0 only): C = A @ B (+bias), generalized scatter
// ---------------------------------------------------------------------------
template<bool TB>
__global__ __launch_bounds__(256) void gemm_tiled(
    const float* __restrict__ A, const float* __restrict__ Bm,
    const float* __restrict__ bias, float* __restrict__ C,
    int M, int N, int K, int lda,
    int P, long long S1, long long S2)
{
  __shared__ float As[16][64 + 1];
  __shared__ float Bs[16][64 + 1];
  const int tid = threadIdx.x;
  const int n0 = blockIdx.x * 64;
  const int r0 = blockIdx.y * 64;
  const int ty = tid / 16;
  const int tx = tid % 16;

  float acc[4][4] = {};

  for (int k0 = 0; k0 < K; k0 += 16) {
    {
      const int kk = tid % 16, m0 = tid / 16;
      #pragma unroll
      for (int i = 0; i < 4; i++) {
        const int m = m0 + i * 16;
        As[kk][m] = A[(long long)(r0 + m) * lda + k0 + kk];
      }
    }
    if (TB) {
      const int kk = tid % 16, nl0 = tid / 16;
      #pragma unroll
      for (int i = 0; i < 4; i++) {
        const int n = nl0 + i * 16;
        Bs[kk][n] = Bm[(long long)(n0 + n) * K + k0 + kk];
      }
    } else {
      const int nl = tid % 64, kk0 = tid / 64;
      #pragma unroll
      for (int i = 0; i < 4; i++) {
        const int kk = kk0 + i * 4;
        Bs[kk][nl] = Bm[(long long)(k0 + kk) * N + n0 + nl];
      }
    }
    __syncthreads();

    #pragma unroll
    for (int kk = 0; kk < 16; kk++) {
      float av[4], bv[4];
      #pragma unroll
      for (int i = 0; i < 4; i++) av[i] = As[kk][ty * 4 + i];
      #pragma unroll
      for (int j = 0; j < 4; j++) bv[j] = Bs[kk][tx * 4 + j];
      #pragma unroll
      for (int i = 0; i < 4; i++)
        #pragma unroll
        for (int j = 0; j < 4; j++)
          acc[i][j] += av[i] * bv[j];
    }
    __syncthreads();
  }

  #pragma unroll
  for (int i = 0; i < 4; i++) {
    const int r = r0 + ty * 4 + i;
    const long long base = (long long)(r % P) * S1 + (long long)(r / P) * S2;
    #pragma unroll
    for (int j = 0; j < 4; j++) {
      const int c = n0 + tx * 4 + j;
      float v = acc[i][j];
      if (bias) v += bias[c];
      C[base + c] = v;
    }
  }
}

// ---------------------------------------------------------------------------
// MFMA f16 GEMM (R13-verified): C[scatter(r), c] = sum_k A[r,k]*B[c,k] + bias
// ---------------------------------------------------------------------------
__global__ __launch_bounds__(256) void gemm_mfma(
    const uint32_t* __restrict__ A16, const uint32_t* __restrict__ B16,
    const float* __restrict__ bias, float* __restrict__ C,
    int K2w, int P, long long S1, long long S2)
{
  __shared__ uint32_t Al[128 * 20];
  __shared__ uint32_t Bl[128 * 20];
  const int tid  = threadIdx.x;
  const int r0   = blockIdx.y * 128;
  const int c0   = blockIdx.x * 128;
  const int wv   = tid >> 6, lane = tid & 63;
  const int wrow = wv >> 1, wcol = wv & 1;
  const int row16 = lane & 15, kg = lane >> 4;

  const int srow = tid >> 1;
  const int scol = (tid & 1) * 8;

  f32x4 acc[4][4];
  #pragma unroll
  for (int a = 0; a < 4; ++a)
    #pragma unroll
    for (int b = 0; b < 4; ++b) acc[a][b] = (f32x4){0.f, 0.f, 0.f, 0.f};

  const int nkt = K2w / 16;
  for (int kt = 0; kt < nkt; ++kt) {
    const uint32_t* ag = A16 + (size_t)(r0 + srow) * K2w + kt * 16 + scol;
    const uint32_t* bg = B16 + (size_t)(c0 + srow) * K2w + kt * 16 + scol;
    *(uint4*)&Al[srow * 20 + scol]     = *(const uint4*)ag;
    *(uint4*)&Al[srow * 20 + scol + 4] = *(const uint4*)(ag + 4);
    *(uint4*)&Bl[srow * 20 + scol]     = *(const uint4*)bg;
    *(uint4*)&Bl[srow * 20 + scol + 4] = *(const uint4*)(bg + 4);
    __syncthreads();

    uint4 af[4], bf[4];
    #pragma unroll
    for (int f = 0; f < 4; ++f) {
      af[f] = *(const uint4*)&Al[(wrow * 64 + f * 16 + row16) * 20 + kg * 4];
      bf[f] = *(const uint4*)&Bl[(wcol * 64 + f * 16 + row16) * 20 + kg * 4];
    }
    #pragma unroll
    for (int fr = 0; fr < 4; ++fr)
      #pragma unroll
      for (int fc = 0; fc < 4; ++fc)
        acc[fr][fc] = __builtin_amdgcn_mfma_f32_16x16x32_f16(
            __builtin_bit_cast(f16x8, af[fr]), __builtin_bit_cast(f16x8, bf[fc]),
            acc[fr][fc], 0, 0, 0);
    __syncthreads();
  }

  #pragma unroll
  for (int fr = 0; fr < 4; ++fr) {
    #pragma unroll
    for (int reg = 0; reg < 4; ++reg) {
      const int rg = r0 + wrow * 64 + fr * 16 + kg * 4 + reg;
      const long long base = (long long)(rg % P) * S1 + (long long)(rg / P) * S2;
      #pragma unroll
      for (int fc = 0; fc < 4; ++fc) {
        const int cg = c0 + wcol * 64 + fc * 16 + row16;
        C[base + cg] = acc[fr][fc][reg] + (bias ? bias[cg] : 0.f);
      }
    }
  }
}

// bias_eff[h] = b_cell[h] + dot(W_x[h,:], b_in)
__global__ void bias_eff_kernel(const float* __restrict__ Wx,
                                const float* __restrict__ b_in,
                                const float* __restrict__ b_cell,
                                float* __restrict__ bias_eff)
{
  const int h = blockIdx.x * 256 + threadIdx.x;
  float s = b_cell[h];
  for (int k = 0; k < SEN; k++) s += Wx[h * SEN + k] * b_in[k];
  bias_eff[h] = s;
}

// Generic f32 -> f16-pair pack
__global__ __launch_bounds__(256) void pack16_kernel(
    const float* __restrict__ in, uint32_t* __restrict__ outp)
{
  const size_t idx = (size_t)blockIdx.x * 256 + threadIdx.x;
  const float2 v = *(const float2*)(in + idx * 2);
  outp[idx] = pk16(v.x, v.y);
}

// Fill hx parity-0 with TAG-0 init_h: u64 idx = (j2>>2)*128 + b*4 + (j2&3)
__global__ __launch_bounds__(256) void init_hx_kernel(
    const float* __restrict__ init_h, unsigned long long* __restrict__ hx0)
{
  const int idx = blockIdx.x * 256 + threadIdx.x;      // b*512 + j2
  const int b  = idx >> 9;
  const int j2 = idx & 511;
  const float2 v = *(const float2*)(init_h + (size_t)b * HID + 2 * j2);
  hx0[(j2 >> 2) * 128 + b * 4 + (j2 & 3)] = (unsigned long long)pk16(v.x, v.y);
}

// ---------------------------------------------------------------------------
// Scan v13: TAGGED exchange (u64 {tag=step, f16-pair}) + R15 publisher tail.
// Readers self-sync by polling their own A-words until tag==t (poll IS the
// load). Bounded-spin FALLBACK: after 2048 failed polls, wait the proven
// R15 flag condition (flags[z] >= t for all z), then accept data untagged.
// Publisher tail unchanged from R15: tagged stores -> __syncthreads (vmcnt
// drain) -> flag post -> hseq16/prefetch. One barrier per step.
// ---------------------------------------------------------------------------
__global__ __launch_bounds__(256, 1) void scan_x_kernel(
    const float* __restrict__ init_h,
    const uint32_t* __restrict__ Wp16,   // [HID][K2]
    const float* __restrict__ pre,       // [T][B][HID]
    const float* __restrict__ tsp,       // [B][T]
    const float* __restrict__ Avec,
    const float* __restrict__ tau,
    uint32_t* __restrict__ hseq16,       // [T][B][256] f16 pairs
    unsigned long long* __restrict__ hx, // [2][PARSZ] tagged
    uint32_t* __restrict__ flags,        // [NBLK][16]
    float* __restrict__ last_state)      // [B][HID]
{
  __shared__ uint32_t w_lds[JSL * WPAD];   // 66 KB

  const int bk   = blockIdx.x;
  const int tid  = threadIdx.x;
  const int wv   = tid >> 6;
  const int lane = tid & 63;
  const int qr   = wv >> 1;
  const int qc   = wv & 1;
  const int row16 = lane & 15;
  const int kg    = lane >> 4;

  const int j_loc  = qc * 16 + row16;
  const int j_glob = bk * JSL + j_loc;
  const int b0     = qr * 16 + kg * 4;

  {
    const uint32_t* src = Wp16 + (size_t)bk * JSL * K2;
    for (int i = tid; i < JSL * K2; i += 256)
      w_lds[(i >> 9) * WPAD + (i & (K2 - 1))] = src[i];
  }

  const float a_j  = Avec[j_glob];
  const float it_j = 1.f / tau[j_glob];
  float h_old[4];
  #pragma unroll
  for (int r = 0; r < 4; ++r) h_old[r] = init_h[(b0 + r) * HID + j_glob];

  float prevC[4], tsC[4];
  #pragma unroll
  for (int r = 0; r < 4; ++r) {
    prevC[r] = pre[(size_t)(b0 + r) * HID + j_glob];
    tsC[r]   = tsp[(b0 + r) * T_SZ + 0];
  }

  __syncthreads();   // w_lds ready

  const uint32_t* brow = &w_lds[j_loc * WPAD];
  const int ab4 = (qr * 16 + row16) * 4;            // u64 base within chunk
  const int pub_base = (j_glob >> 3) * 128 + ((j_glob >> 1) & 3);

  for (int t = 0; t < T_SZ; ++t) {
    const unsigned long long* hxr = hx + (size_t)(t & 1) * PARSZ;
    const uint32_t tg = (uint32_t)t;
    bool trusted = false;

    f32x4 acc = {0.f, 0.f, 0.f, 0.f};

    #pragma unroll
    for (int kb = 0; kb < 4; ++kb) {
      unsigned long long a[32];
      int spin = 0;
      while (true) {
        #pragma unroll
        for (int i = 0; i < 8; ++i) {
          const int kk = kb * 8 + i;
          const size_t base = (size_t)(kk * 4 + kg) * 128 + ab4;
          #pragma unroll
          for (int w = 0; w < 4; ++w)
            a[i * 4 + w] = __hip_atomic_load(&hxr[base + w],
                             __ATOMIC_RELAXED, __HIP_MEMORY_SCOPE_AGENT);
        }
        if (trusted) break;
        bool ok = true;
        #pragma unroll
        for (int i = 0; i < 32; ++i)
          ok &= ((uint32_t)(a[i] >> 32) == tg);
        if (__all(ok)) break;
        if (++spin > 2048) {
          // fallback: proven R15 flag condition, then accept untagged
          while (true) {
            const uint32_t v = __hip_atomic_load(&flags[(lane & 31) * 16],
                                 __ATOMIC_RELAXED, __HIP_MEMORY_SCOPE_AGENT);
            if (__all(v >= tg)) break;
            __builtin_amdgcn_s_sleep(8);
          }
          trusted = true;          // next pass reloads once and breaks
        } else {
          __builtin_amdgcn_s_sleep(1);
        }
      }
      #pragma unroll
      for (int i = 0; i < 8; ++i) {
        const int kk = kb * 8 + i;
        const uint4 av = make_uint4((uint32_t)a[i * 4 + 0], (uint32_t)a[i * 4 + 1],
                                    (uint32_t)a[i * 4 + 2], (uint32_t)a[i * 4 + 3]);
        const uint4 bv = *(const uint4*)(brow + kk * 16 + kg * 4);
        acc = __builtin_amdgcn_mfma_f32_16x16x32_f16(
            __builtin_bit_cast(f16x8, av), __builtin_bit_cast(f16x8, bv),
            acc, 0, 0, 0);
      }
    }

    float hn[4];
    #pragma unroll
    for (int r = 0; r < 4; ++r) {
      const float z = acc[r] + prevC[r];
      const float f = 1.f / (1.f + __expf(-z));
      hn[r] = (h_old[r] + tsC[r] * f * a_j) / (1.f + tsC[r] * (it_j + f));
      h_old[r] = hn[r];
    }

    uint32_t pkv[4];
    #pragma unroll
    for (int r = 0; r < 4; ++r) {
      const float partner = __shfl_xor(hn[r], 1);
      pkv[r] = pk16(hn[r], partner);
    }

    // tagged publishes (tag+data land atomically together)
    unsigned long long* hxw = hx + (size_t)((t + 1) & 1) * PARSZ;
    const unsigned long long tagv = ((unsigned long long)(t + 1)) << 32;
    if ((row16 & 1) == 0) {
      #pragma unroll
      for (int r = 0; r < 4; ++r)
        __hip_atomic_store(&hxw[pub_base + (b0 + r) * 4],
                           tagv | (unsigned long long)pkv[r],
                           __ATOMIC_RELAXED, __HIP_MEMORY_SCOPE_AGENT);
    }

    __syncthreads();   // drain publishes (keeps flag semantics = R15)

    if (tid == 0)
      __hip_atomic_store(&flags[bk * 16], (uint32_t)(t + 1),
                         __ATOMIC_RELAXED, __HIP_MEMORY_SCOPE_AGENT);

    // off-critical-path: hseq16 + next-step prefetch
    if (bk < 16 && (row16 & 1) == 0) {
      #pragma unroll
      for (int r = 0; r < 4; ++r)
        hseq16[(size_t)t * (B_SZ * 256) + (b0 + r) * 256 + (j_glob >> 1)] = pkv[r];
    }
    const int tn = (t + 1 < T_SZ) ? t + 1 : t;
    #pragma unroll
    for (int r = 0; r < 4; ++r) {
      prevC[r] = pre[(size_t)tn * (B_SZ * HID) + (b0 + r) * HID + j_glob];
      tsC[r]   = tsp[(b0 + r) * T_SZ + tn];
    }
  }

  #pragma unroll
  for (int r = 0; r < 4; ++r)
    last_state[(b0 + r) * HID + j_glob] = h_old[r];
}

extern "C" void kernel_launch(void* const* d_in, const int* in_sizes, int n_in,
                              void* d_out, int out_size, void* d_ws, size_t ws_size,
                              hipStream_t stream)
{
  const float* inputs    = (const float*)d_in[0];
  const float* timespans = (const float*)d_in[1];
  const float* init_h    = (const float*)d_in[2];
  const float* W_in      = (const float*)d_in[3];
  const float* b_in      = (const float*)d_in[4];
  const float* W_x       = (const float*)d_in[5];
  const float* W_h       = (const float*)d_in[6];
  const float* b_cell    = (const float*)d_in[7];
  const float* tau       = (const float*)d_in[8];
  const float* A         = (const float*)d_in[9];
  const float* W_out     = (const float*)d_in[10];
  const float* b_out     = (const float*)d_in[11];
  float* out = (float*)d_out;

  float*    ws     = (float*)d_ws;
  float*    pre    = ws;
  uint32_t* hseq16 = (uint32_t*)(pre + (size_t)T_SZ * B_SZ * HID);
  uint32_t* in16   = hseq16 + (size_t)T_SZ * B_SZ * 256;
  float*    Wxi    = (float*)(in16 + (size_t)B_SZ * T_SZ * 256);   // 2 MB; dead after pack -> reused as hx
  uint32_t* wxi16  = (uint32_t*)(Wxi + (size_t)HID * IN_SZ);
  uint32_t* wh16   = wxi16 + (size_t)HID * (IN_SZ / 2);
  uint32_t* wout16 = wh16 + (size_t)HID * K2;
  float*    beff   = (float*)(wout16 + (size_t)OUT_SZ * (MOT / 2));

  // hx (tagged u64, 256 KB) + flags (2 KB) live in the dead Wxi buffer
  unsigned long long* hx    = (unsigned long long*)Wxi;
  uint32_t*           flags = (uint32_t*)(hx + 2 * PARSZ);

  // K0: Wxi = W_x @ W_in (f32)
  gemm_tiled<false><<<dim3(IN_SZ / 64, HID / 64), 256, 0, stream>>>(
      W_x, W_in, nullptr, Wxi, HID, IN_SZ, SEN, SEN,
      1 << 30, (long long)IN_SZ, 0LL);

  bias_eff_kernel<<<HID / 256, 256, 0, stream>>>(W_x, b_in, b_cell, beff);

  // packs (Wxi must be packed BEFORE hx overwrites it)
  pack16_kernel<<<(B_SZ * T_SZ * IN_SZ / 2) / 256, 256, 0, stream>>>(inputs, in16);
  pack16_kernel<<<(HID * IN_SZ / 2) / 256, 256, 0, stream>>>(Wxi, wxi16);
  pack16_kernel<<<(HID * HID / 2) / 256, 256, 0, stream>>>(W_h, wh16);
  pack16_kernel<<<(OUT_SZ * MOT / 2) / 256, 256, 0, stream>>>(W_out, wout16);

  // K1 (MFMA): pre = in16 @ wxi16^T + beff, scattered to [t][b][h]
  gemm_mfma<<<dim3(HID / 128, (B_SZ * T_SZ) / 128), 256, 0, stream>>>(
      in16, wxi16, beff, pre, IN_SZ / 2,
      T_SZ, (long long)B_SZ * HID, (long long)HID);

  // zero hx (both parities -> stale tags killed) + flags, then fill parity-0
  (void)hipMemsetAsync(hx, 0,
                       2 * PARSZ * sizeof(unsigned long long) +
                       NBLK * 16 * sizeof(uint32_t), stream);
  init_hx_kernel<<<(B_SZ * K2) / 256, 256, 0, stream>>>(init_h, hx);

  // scan — 32 co-resident blocks, tagged exchange + flag fallback
  {
    const uint32_t* wh16c = (const uint32_t*)wh16;
    float* last_state = out + (size_t)B_SZ * T_SZ * OUT_SZ;
    void* args[] = {
      (void*)&init_h, (void*)&wh16c, (void*)&pre, (void*)&timespans,
      (void*)&A, (void*)&tau, (void*)&hseq16, (void*)&hx, (void*)&flags,
      (void*)&last_state
    };
    (void)hipLaunchCooperativeKernel((void*)scan_x_kernel, dim3(NBLK), dim3(256),
                                     args, 0, stream);
  }

  // K3 (MFMA): out = hseq16 @ wout16^T + b_out, scattered to [b][t][o]
  gemm_mfma<<<dim3(OUT_SZ / 128, (B_SZ * T_SZ) / 128), 256, 0, stream>>>(
      hseq16, wout16, b_out, out, MOT / 2,
      B_SZ, (long long)T_SZ * OUT_SZ, (long long)OUT_SZ);
}

// Round 17
// 4649.753 us; speedup vs baseline: 1.4990x; 1.4990x over previous
//
#include <hip/hip_runtime.h>
#include <math.h>

#define B_SZ   32
#define T_SZ   1024
#define IN_SZ  512
#define SEN    512
#define HID    1024
#define MOT    512
#define OUT_SZ 512

#define NBLK   32          // scan blocks (j-slices)
#define JSL    32          // j's per block
#define K2     512         // f16-pair dwords per h row
#define WPAD   516         // padded w_lds row stride (dwords)

typedef __fp16  f16x8 __attribute__((ext_vector_type(8)));
typedef float   f32x4 __attribute__((ext_vector_type(4)));

__device__ inline uint32_t pk16(float a, float b) {
  auto p = __builtin_amdgcn_cvt_pkrtz(a, b);
  return __builtin_bit_cast(uint32_t, p);
}

// ---------------------------------------------------------------------------
// f32 tile GEMM (K0 only): C = A @ B (+bias), generalized scatter
// ---------------------------------------------------------------------------
template<bool TB>
__global__ __launch_bounds__(256) void gemm_tiled(
    const float* __restrict__ A, const float* __restrict__ Bm,
    const float* __restrict__ bias, float* __restrict__ C,
    int M, int N, int K, int lda,
    int P, long long S1, long long S2)
{
  __shared__ float As[16][64 + 1];
  __shared__ float Bs[16][64 + 1];
  const int tid = threadIdx.x;
  const int n0 = blockIdx.x * 64;
  const int r0 = blockIdx.y * 64;
  const int ty = tid / 16;
  const int tx = tid % 16;

  float acc[4][4] = {};

  for (int k0 = 0; k0 < K; k0 += 16) {
    {
      const int kk = tid % 16, m0 = tid / 16;
      #pragma unroll
      for (int i = 0; i < 4; i++) {
        const int m = m0 + i * 16;
        As[kk][m] = A[(long long)(r0 + m) * lda + k0 + kk];
      }
    }
    if (TB) {
      const int kk = tid % 16, nl0 = tid / 16;
      #pragma unroll
      for (int i = 0; i < 4; i++) {
        const int n = nl0 + i * 16;
        Bs[kk][n] = Bm[(long long)(n0 + n) * K + k0 + kk];
      }
    } else {
      const int nl = tid % 64, kk0 = tid / 64;
      #pragma unroll
      for (int i = 0; i < 4; i++) {
        const int kk = kk0 + i * 4;
        Bs[kk][nl] = Bm[(long long)(k0 + kk) * N + n0 + nl];
      }
    }
    __syncthreads();

    #pragma unroll
    for (int kk = 0; kk < 16; kk++) {
      float av[4], bv[4];
      #pragma unroll
      for (int i = 0; i < 4; i++) av[i] = As[kk][ty * 4 + i];
      #pragma unroll
      for (int j = 0; j < 4; j++) bv[j] = Bs[kk][tx * 4 + j];
      #pragma unroll
      for (int i = 0; i < 4; i++)
        #pragma unroll
        for (int j = 0; j < 4; j++)
          acc[i][j] += av[i] * bv[j];
    }
    __syncthreads();
  }

  #pragma unroll
  for (int i = 0; i < 4; i++) {
    const int r = r0 + ty * 4 + i;
    const long long base = (long long)(r % P) * S1 + (long long)(r / P) * S2;
    #pragma unroll
    for (int j = 0; j < 4; j++) {
      const int c = n0 + tx * 4 + j;
      float v = acc[i][j];
      if (bias) v += bias[c];
      C[base + c] = v;
    }
  }
}

// ---------------------------------------------------------------------------
// MFMA f16 GEMM (R13-verified): C[scatter(r), c] = sum_k A[r,k]*B[c,k] + bias
// ---------------------------------------------------------------------------
__global__ __launch_bounds__(256) void gemm_mfma(
    const uint32_t* __restrict__ A16, const uint32_t* __restrict__ B16,
    const float* __restrict__ bias, float* __restrict__ C,
    int K2w, int P, long long S1, long long S2)
{
  __shared__ uint32_t Al[128 * 20];
  __shared__ uint32_t Bl[128 * 20];
  const int tid  = threadIdx.x;
  const int r0   = blockIdx.y * 128;
  const int c0   = blockIdx.x * 128;
  const int wv   = tid >> 6, lane = tid & 63;
  const int wrow = wv >> 1, wcol = wv & 1;
  const int row16 = lane & 15, kg = lane >> 4;

  const int srow = tid >> 1;
  const int scol = (tid & 1) * 8;

  f32x4 acc[4][4];
  #pragma unroll
  for (int a = 0; a < 4; ++a)
    #pragma unroll
    for (int b = 0; b < 4; ++b) acc[a][b] = (f32x4){0.f, 0.f, 0.f, 0.f};

  const int nkt = K2w / 16;
  for (int kt = 0; kt < nkt; ++kt) {
    const uint32_t* ag = A16 + (size_t)(r0 + srow) * K2w + kt * 16 + scol;
    const uint32_t* bg = B16 + (size_t)(c0 + srow) * K2w + kt * 16 + scol;
    *(uint4*)&Al[srow * 20 + scol]     = *(const uint4*)ag;
    *(uint4*)&Al[srow * 20 + scol + 4] = *(const uint4*)(ag + 4);
    *(uint4*)&Bl[srow * 20 + scol]     = *(const uint4*)bg;
    *(uint4*)&Bl[srow * 20 + scol + 4] = *(const uint4*)(bg + 4);
    __syncthreads();

    uint4 af[4], bf[4];
    #pragma unroll
    for (int f = 0; f < 4; ++f) {
      af[f] = *(const uint4*)&Al[(wrow * 64 + f * 16 + row16) * 20 + kg * 4];
      bf[f] = *(const uint4*)&Bl[(wcol * 64 + f * 16 + row16) * 20 + kg * 4];
    }
    #pragma unroll
    for (int fr = 0; fr < 4; ++fr)
      #pragma unroll
      for (int fc = 0; fc < 4; ++fc)
        acc[fr][fc] = __builtin_amdgcn_mfma_f32_16x16x32_f16(
            __builtin_bit_cast(f16x8, af[fr]), __builtin_bit_cast(f16x8, bf[fc]),
            acc[fr][fc], 0, 0, 0);
    __syncthreads();
  }

  #pragma unroll
  for (int fr = 0; fr < 4; ++fr) {
    #pragma unroll
    for (int reg = 0; reg < 4; ++reg) {
      const int rg = r0 + wrow * 64 + fr * 16 + kg * 4 + reg;
      const long long base = (long long)(rg % P) * S1 + (long long)(rg / P) * S2;
      #pragma unroll
      for (int fc = 0; fc < 4; ++fc) {
        const int cg = c0 + wcol * 64 + fc * 16 + row16;
        C[base + cg] = acc[fr][fc][reg] + (bias ? bias[cg] : 0.f);
      }
    }
  }
}

// bias_eff[h] = b_cell[h] + dot(W_x[h,:], b_in)
__global__ void bias_eff_kernel(const float* __restrict__ Wx,
                                const float* __restrict__ b_in,
                                const float* __restrict__ b_cell,
                                float* __restrict__ bias_eff)
{
  const int h = blockIdx.x * 256 + threadIdx.x;
  float s = b_cell[h];
  for (int k = 0; k < SEN; k++) s += Wx[h * SEN + k] * b_in[k];
  bias_eff[h] = s;
}

// Generic f32 -> f16-pair pack
__global__ __launch_bounds__(256) void pack16_kernel(
    const float* __restrict__ in, uint32_t* __restrict__ outp)
{
  const size_t idx = (size_t)blockIdx.x * 256 + threadIdx.x;
  const float2 v = *(const float2*)(in + idx * 2);
  outp[idx] = pk16(v.x, v.y);
}

// Pack init_h -> hx[0] fragment-major: u32 idx = (j2>>2)*128 + b*4 + (j2&3)
__global__ __launch_bounds__(256) void init_hx_kernel(
    const float* __restrict__ init_h, uint32_t* __restrict__ hx0)
{
  const int idx = blockIdx.x * 256 + threadIdx.x;
  const int b  = idx >> 9;
  const int j2 = idx & 511;
  const float2 v = *(const float2*)(init_h + (size_t)b * HID + 2 * j2);
  hx0[(j2 >> 2) * 128 + b * 4 + (j2 & 3)] = pk16(v.x, v.y);
}

// ---------------------------------------------------------------------------
// Scan v14 = R15 exchange (u32 frag-major hx + 32 block flags) with
// WAVE-AUTONOMOUS sync: zero in-loop __syncthreads.
//   per wave per step:
//     poll all 32 flags >= t (every wave polls; flag lines stay LLC-resident)
//     -> A-loads -> 32 MFMA -> update -> 4 hx publishes
//     -> s_waitcnt vmcnt(0)  (wave's own reads+publishes at coherence point)
//     -> ds_add tally (monotonic LDS counter)
//     -> wave 0: spin tally >= 4*(t+1)  (LDS, ~50ns), post flags[bk]=t+1
//     -> hseq16 + pre/ts prefetch (off critical path)
// flag[bk]=t+1 still implies all 4 waves' publishes drained (same invariant
// as R15); overwrite-safety induction unchanged.
// ---------------------------------------------------------------------------
__global__ __launch_bounds__(256, 1) void scan_x_kernel(
    const float* __restrict__ init_h,
    const uint32_t* __restrict__ Wp16,   // [HID][K2]
    const float* __restrict__ pre,       // [T][B][HID]
    const float* __restrict__ tsp,       // [B][T]
    const float* __restrict__ Avec,
    const float* __restrict__ tau,
    uint32_t* __restrict__ hseq16,       // [T][B][256] f16 pairs
    uint32_t* __restrict__ hx,           // [2][B_SZ*K2] fragment-major
    uint32_t* __restrict__ flags,        // [NBLK][16]
    float* __restrict__ last_state)      // [B][HID]
{
  __shared__ uint32_t w_lds[JSL * WPAD];   // 66 KB
  __shared__ uint32_t tally;               // monotonic wave-completion counter

  const int bk   = blockIdx.x;
  const int tid  = threadIdx.x;
  const int wv   = tid >> 6;
  const int lane = tid & 63;
  const int qr   = wv >> 1;
  const int qc   = wv & 1;
  const int row16 = lane & 15;
  const int kg    = lane >> 4;

  const int j_loc  = qc * 16 + row16;
  const int j_glob = bk * JSL + j_loc;
  const int b0     = qr * 16 + kg * 4;

  if (tid == 0) tally = 0;
  {
    const uint32_t* src = Wp16 + (size_t)bk * JSL * K2;
    for (int i = tid; i < JSL * K2; i += 256)
      w_lds[(i >> 9) * WPAD + (i & (K2 - 1))] = src[i];
  }

  const float a_j  = Avec[j_glob];
  const float it_j = 1.f / tau[j_glob];
  float h_old[4];
  #pragma unroll
  for (int r = 0; r < 4; ++r) h_old[r] = init_h[(b0 + r) * HID + j_glob];

  float prevC[4], tsC[4];
  #pragma unroll
  for (int r = 0; r < 4; ++r) {
    prevC[r] = pre[(size_t)(b0 + r) * HID + j_glob];
    tsC[r]   = tsp[(b0 + r) * T_SZ + 0];
  }

  __syncthreads();   // w_lds + tally ready (only barrier in the kernel)

  const uint32_t* brow = &w_lds[j_loc * WPAD];
  const int ab2 = (qr * 16 + row16) * 2;            // u64 base within chunk
  const int pub_base = (j_glob >> 3) * 128 + ((j_glob >> 1) & 3);

  for (int t = 0; t < T_SZ; ++t) {
    // every wave polls all 32 block flags itself (no broadcast barrier)
    if (t > 0) {
      const uint32_t tgt = (uint32_t)t;
      while (true) {
        const uint32_t v = __hip_atomic_load(&flags[(lane & 31) * 16],
                             __ATOMIC_RELAXED, __HIP_MEMORY_SCOPE_AGENT);
        if (__all(v >= tgt)) break;
        __builtin_amdgcn_s_sleep(1);
      }
    }

    // A fragments (coalesced coherent 8B loads)
    const unsigned long long* hxr =
        (const unsigned long long*)(hx + (t & 1) * (B_SZ * K2));
    unsigned long long a64[64];
    #pragma unroll
    for (int kk = 0; kk < 32; ++kk) {
      const size_t base = (size_t)(kk * 4 + kg) * 64 + ab2;
      a64[2 * kk]     = __hip_atomic_load(&hxr[base],
                          __ATOMIC_RELAXED, __HIP_MEMORY_SCOPE_AGENT);
      a64[2 * kk + 1] = __hip_atomic_load(&hxr[base + 1],
                          __ATOMIC_RELAXED, __HIP_MEMORY_SCOPE_AGENT);
    }

    f32x4 acc = {0.f, 0.f, 0.f, 0.f};
    #pragma unroll
    for (int kk = 0; kk < 32; ++kk) {
      const uint4 av = make_uint4((uint32_t)a64[2 * kk],
                                  (uint32_t)(a64[2 * kk] >> 32),
                                  (uint32_t)a64[2 * kk + 1],
                                  (uint32_t)(a64[2 * kk + 1] >> 32));
      const uint4 bv = *(const uint4*)(brow + kk * 16 + kg * 4);
      acc = __builtin_amdgcn_mfma_f32_16x16x32_f16(
          __builtin_bit_cast(f16x8, av), __builtin_bit_cast(f16x8, bv),
          acc, 0, 0, 0);
    }

    float hn[4];
    #pragma unroll
    for (int r = 0; r < 4; ++r) {
      const float z = acc[r] + prevC[r];
      const float f = 1.f / (1.f + __expf(-z));
      hn[r] = (h_old[r] + tsC[r] * f * a_j) / (1.f + tsC[r] * (it_j + f));
      h_old[r] = hn[r];
    }

    uint32_t pkv[4];
    #pragma unroll
    for (int r = 0; r < 4; ++r) {
      const float partner = __shfl_xor(hn[r], 1);
      pkv[r] = pk16(hn[r], partner);
    }

    // critical path: publishes -> own drain -> tally -> (wave0) flag post
    uint32_t* hxw = hx + ((t + 1) & 1) * (B_SZ * K2);
    if ((row16 & 1) == 0) {
      #pragma unroll
      for (int r = 0; r < 4; ++r)
        __hip_atomic_store(&hxw[pub_base + (b0 + r) * 4], pkv[r],
                           __ATOMIC_RELAXED, __HIP_MEMORY_SCOPE_AGENT);
    }
    asm volatile("s_waitcnt vmcnt(0)" ::: "memory");   // my publishes drained

    if (lane == 0)
      __hip_atomic_fetch_add(&tally, 1u,
                             __ATOMIC_RELAXED, __HIP_MEMORY_SCOPE_WORKGROUP);
    if (wv == 0 && lane == 0) {
      const uint32_t want = 4u * (uint32_t)(t + 1);
      while (__hip_atomic_load(&tally,
                               __ATOMIC_RELAXED, __HIP_MEMORY_SCOPE_WORKGROUP) < want)
        ;
      __hip_atomic_store(&flags[bk * 16], (uint32_t)(t + 1),
                         __ATOMIC_RELAXED, __HIP_MEMORY_SCOPE_AGENT);
    }

    // off-critical-path: hseq16 + next-step prefetch
    if (bk < 16 && (row16 & 1) == 0) {
      #pragma unroll
      for (int r = 0; r < 4; ++r)
        hseq16[(size_t)t * (B_SZ * 256) + (b0 + r) * 256 + (j_glob >> 1)] = pkv[r];
    }
    const int tn = (t + 1 < T_SZ) ? t + 1 : t;
    #pragma unroll
    for (int r = 0; r < 4; ++r) {
      prevC[r] = pre[(size_t)tn * (B_SZ * HID) + (b0 + r) * HID + j_glob];
      tsC[r]   = tsp[(b0 + r) * T_SZ + tn];
    }
  }

  #pragma unroll
  for (int r = 0; r < 4; ++r)
    last_state[(b0 + r) * HID + j_glob] = h_old[r];
}

extern "C" void kernel_launch(void* const* d_in, const int* in_sizes, int n_in,
                              void* d_out, int out_size, void* d_ws, size_t ws_size,
                              hipStream_t stream)
{
  const float* inputs    = (const float*)d_in[0];
  const float* timespans = (const float*)d_in[1];
  const float* init_h    = (const float*)d_in[2];
  const float* W_in      = (const float*)d_in[3];
  const float* b_in      = (const float*)d_in[4];
  const float* W_x       = (const float*)d_in[5];
  const float* W_h       = (const float*)d_in[6];
  const float* b_cell    = (const float*)d_in[7];
  const float* tau       = (const float*)d_in[8];
  const float* A         = (const float*)d_in[9];
  const float* W_out     = (const float*)d_in[10];
  const float* b_out     = (const float*)d_in[11];
  float* out = (float*)d_out;

  float*    ws     = (float*)d_ws;
  float*    pre    = ws;
  uint32_t* hseq16 = (uint32_t*)(pre + (size_t)T_SZ * B_SZ * HID);
  uint32_t* in16   = hseq16 + (size_t)T_SZ * B_SZ * 256;
  float*    Wxi    = (float*)(in16 + (size_t)B_SZ * T_SZ * 256);
  uint32_t* wxi16  = (uint32_t*)(Wxi + (size_t)HID * IN_SZ);
  uint32_t* wh16   = wxi16 + (size_t)HID * (IN_SZ / 2);
  uint32_t* wout16 = wh16 + (size_t)HID * K2;
  float*    beff   = (float*)(wout16 + (size_t)OUT_SZ * (MOT / 2));
  uint32_t* hx     = (uint32_t*)(beff + HID);
  uint32_t* flags  = hx + 2 * B_SZ * K2;                 // NBLK*16 u32

  // K0: Wxi = W_x @ W_in (f32)
  gemm_tiled<false><<<dim3(IN_SZ / 64, HID / 64), 256, 0, stream>>>(
      W_x, W_in, nullptr, Wxi, HID, IN_SZ, SEN, SEN,
      1 << 30, (long long)IN_SZ, 0LL);

  bias_eff_kernel<<<HID / 256, 256, 0, stream>>>(W_x, b_in, b_cell, beff);

  // packs
  pack16_kernel<<<(B_SZ * T_SZ * IN_SZ / 2) / 256, 256, 0, stream>>>(inputs, in16);
  pack16_kernel<<<(HID * IN_SZ / 2) / 256, 256, 0, stream>>>(Wxi, wxi16);
  pack16_kernel<<<(HID * HID / 2) / 256, 256, 0, stream>>>(W_h, wh16);
  pack16_kernel<<<(OUT_SZ * MOT / 2) / 256, 256, 0, stream>>>(W_out, wout16);

  // K1 (MFMA): pre = in16 @ wxi16^T + beff, scattered to [t][b][h]
  gemm_mfma<<<dim3(HID / 128, (B_SZ * T_SZ) / 128), 256, 0, stream>>>(
      in16, wxi16, beff, pre, IN_SZ / 2,
      T_SZ, (long long)B_SZ * HID, (long long)HID);

  // init exchange parity-0; zero flags
  init_hx_kernel<<<(B_SZ * K2) / 256, 256, 0, stream>>>(init_h, hx);
  (void)hipMemsetAsync(flags, 0, NBLK * 16 * sizeof(uint32_t), stream);

  // scan — 32 co-resident blocks, wave-autonomous flag protocol
  {
    const uint32_t* wh16c = (const uint32_t*)wh16;
    float* last_state = out + (size_t)B_SZ * T_SZ * OUT_SZ;
    void* args[] = {
      (void*)&init_h, (void*)&wh16c, (void*)&pre, (void*)&timespans,
      (void*)&A, (void*)&tau, (void*)&hseq16, (void*)&hx, (void*)&flags,
      (void*)&last_state
    };
    (void)hipLaunchCooperativeKernel((void*)scan_x_kernel, dim3(NBLK), dim3(256),
                                     args, 0, stream);
  }

  // K3 (MFMA): out = hseq16 @ wout16^T + b_out, scattered to [b][t][o]
  gemm_mfma<<<dim3(OUT_SZ / 128, (B_SZ * T_SZ) / 128), 256, 0, stream>>>(
      hseq16, wout16, b_out, out, MOT / 2,
      B_SZ, (long long)T_SZ * OUT_SZ, (long long)OUT_SZ);
}

// Round 18
// 3947.401 us; speedup vs baseline: 1.7657x; 1.1779x over previous
//
#include <hip/hip_runtime.h>
#include <math.h>

#define B_SZ   32
#define T_SZ   1024
#define IN_SZ  512
#define SEN    512
#define HID    1024
#define MOT    512
#define OUT_SZ 512

#define NBLK   32          // scan blocks (j-slices)
#define JSL    32          // j's per block
#define K2     512         // f16-pair dwords per h row
#define WPAD   516         // padded w_lds row stride (dwords)

typedef __fp16  f16x8 __attribute__((ext_vector_type(8)));
typedef float   f32x4 __attribute__((ext_vector_type(4)));

__device__ inline uint32_t pk16(float a, float b) {
  auto p = __builtin_amdgcn_cvt_pkrtz(a, b);
  return __builtin_bit_cast(uint32_t, p);
}

// ---------------------------------------------------------------------------
// f32 tile GEMM (K0 only): C = A @ B (+bias), generalized scatter
// ---------------------------------------------------------------------------
template<bool TB>
__global__ __launch_bounds__(256) void gemm_tiled(
    const float* __restrict__ A, const float* __restrict__ Bm,
    const float* __restrict__ bias, float* __restrict__ C,
    int M, int N, int K, int lda,
    int P, long long S1, long long S2)
{
  __shared__ float As[16][64 + 1];
  __shared__ float Bs[16][64 + 1];
  const int tid = threadIdx.x;
  const int n0 = blockIdx.x * 64;
  const int r0 = blockIdx.y * 64;
  const int ty = tid / 16;
  const int tx = tid % 16;

  float acc[4][4] = {};

  for (int k0 = 0; k0 < K; k0 += 16) {
    {
      const int kk = tid % 16, m0 = tid / 16;
      #pragma unroll
      for (int i = 0; i < 4; i++) {
        const int m = m0 + i * 16;
        As[kk][m] = A[(long long)(r0 + m) * lda + k0 + kk];
      }
    }
    if (TB) {
      const int kk = tid % 16, nl0 = tid / 16;
      #pragma unroll
      for (int i = 0; i < 4; i++) {
        const int n = nl0 + i * 16;
        Bs[kk][n] = Bm[(long long)(n0 + n) * K + k0 + kk];
      }
    } else {
      const int nl = tid % 64, kk0 = tid / 64;
      #pragma unroll
      for (int i = 0; i < 4; i++) {
        const int kk = kk0 + i * 4;
        Bs[kk][nl] = Bm[(long long)(k0 + kk) * N + n0 + nl];
      }
    }
    __syncthreads();

    #pragma unroll
    for (int kk = 0; kk < 16; kk++) {
      float av[4], bv[4];
      #pragma unroll
      for (int i = 0; i < 4; i++) av[i] = As[kk][ty * 4 + i];
      #pragma unroll
      for (int j = 0; j < 4; j++) bv[j] = Bs[kk][tx * 4 + j];
      #pragma unroll
      for (int i = 0; i < 4; i++)
        #pragma unroll
        for (int j = 0; j < 4; j++)
          acc[i][j] += av[i] * bv[j];
    }
    __syncthreads();
  }

  #pragma unroll
  for (int i = 0; i < 4; i++) {
    const int r = r0 + ty * 4 + i;
    const long long base = (long long)(r % P) * S1 + (long long)(r / P) * S2;
    #pragma unroll
    for (int j = 0; j < 4; j++) {
      const int c = n0 + tx * 4 + j;
      float v = acc[i][j];
      if (bias) v += bias[c];
      C[base + c] = v;
    }
  }
}

// ---------------------------------------------------------------------------
// MFMA f16 GEMM (R13-verified): C[scatter(r), c] = sum_k A[r,k]*B[c,k] + bias
// ---------------------------------------------------------------------------
__global__ __launch_bounds__(256) void gemm_mfma(
    const uint32_t* __restrict__ A16, const uint32_t* __restrict__ B16,
    const float* __restrict__ bias, float* __restrict__ C,
    int K2w, int P, long long S1, long long S2)
{
  __shared__ uint32_t Al[128 * 20];
  __shared__ uint32_t Bl[128 * 20];
  const int tid  = threadIdx.x;
  const int r0   = blockIdx.y * 128;
  const int c0   = blockIdx.x * 128;
  const int wv   = tid >> 6, lane = tid & 63;
  const int wrow = wv >> 1, wcol = wv & 1;
  const int row16 = lane & 15, kg = lane >> 4;

  const int srow = tid >> 1;
  const int scol = (tid & 1) * 8;

  f32x4 acc[4][4];
  #pragma unroll
  for (int a = 0; a < 4; ++a)
    #pragma unroll
    for (int b = 0; b < 4; ++b) acc[a][b] = (f32x4){0.f, 0.f, 0.f, 0.f};

  const int nkt = K2w / 16;
  for (int kt = 0; kt < nkt; ++kt) {
    const uint32_t* ag = A16 + (size_t)(r0 + srow) * K2w + kt * 16 + scol;
    const uint32_t* bg = B16 + (size_t)(c0 + srow) * K2w + kt * 16 + scol;
    *(uint4*)&Al[srow * 20 + scol]     = *(const uint4*)ag;
    *(uint4*)&Al[srow * 20 + scol + 4] = *(const uint4*)(ag + 4);
    *(uint4*)&Bl[srow * 20 + scol]     = *(const uint4*)bg;
    *(uint4*)&Bl[srow * 20 + scol + 4] = *(const uint4*)(bg + 4);
    __syncthreads();

    uint4 af[4], bf[4];
    #pragma unroll
    for (int f = 0; f < 4; ++f) {
      af[f] = *(const uint4*)&Al[(wrow * 64 + f * 16 + row16) * 20 + kg * 4];
      bf[f] = *(const uint4*)&Bl[(wcol * 64 + f * 16 + row16) * 20 + kg * 4];
    }
    #pragma unroll
    for (int fr = 0; fr < 4; ++fr)
      #pragma unroll
      for (int fc = 0; fc < 4; ++fc)
        acc[fr][fc] = __builtin_amdgcn_mfma_f32_16x16x32_f16(
            __builtin_bit_cast(f16x8, af[fr]), __builtin_bit_cast(f16x8, bf[fc]),
            acc[fr][fc], 0, 0, 0);
    __syncthreads();
  }

  #pragma unroll
  for (int fr = 0; fr < 4; ++fr) {
    #pragma unroll
    for (int reg = 0; reg < 4; ++reg) {
      const int rg = r0 + wrow * 64 + fr * 16 + kg * 4 + reg;
      const long long base = (long long)(rg % P) * S1 + (long long)(rg / P) * S2;
      #pragma unroll
      for (int fc = 0; fc < 4; ++fc) {
        const int cg = c0 + wcol * 64 + fc * 16 + row16;
        C[base + cg] = acc[fr][fc][reg] + (bias ? bias[cg] : 0.f);
      }
    }
  }
}

// bias_eff[h] = b_cell[h] + dot(W_x[h,:], b_in)
__global__ void bias_eff_kernel(const float* __restrict__ Wx,
                                const float* __restrict__ b_in,
                                const float* __restrict__ b_cell,
                                float* __restrict__ bias_eff)
{
  const int h = blockIdx.x * 256 + threadIdx.x;
  float s = b_cell[h];
  for (int k = 0; k < SEN; k++) s += Wx[h * SEN + k] * b_in[k];
  bias_eff[h] = s;
}

// Generic f32 -> f16-pair pack
__global__ __launch_bounds__(256) void pack16_kernel(
    const float* __restrict__ in, uint32_t* __restrict__ outp)
{
  const size_t idx = (size_t)blockIdx.x * 256 + threadIdx.x;
  const float2 v = *(const float2*)(in + idx * 2);
  outp[idx] = pk16(v.x, v.y);
}

// Pack init_h -> hx[0] fragment-major: u32 idx = (j2>>2)*128 + b*4 + (j2&3)
__global__ __launch_bounds__(256) void init_hx_kernel(
    const float* __restrict__ init_h, uint32_t* __restrict__ hx0)
{
  const int idx = blockIdx.x * 256 + threadIdx.x;
  const int b  = idx >> 9;
  const int j2 = idx & 511;
  const float2 v = *(const float2*)(init_h + (size_t)b * HID + 2 * j2);
  hx0[(j2 >> 2) * 128 + b * 4 + (j2 & 3)] = pk16(v.x, v.y);
}

// ---------------------------------------------------------------------------
// Scan v12 (R15, measured optimum): block flags + 2 syncthreads, slim drain.
// ONLY the 4 hx publishes sit before the drain-sync + flag post; hseq16
// stores and pre/ts prefetch after the flag post (complete under next poll).
// Protocol bracketing: R13 full-drain 3.93 / R14 per-wave-flags 4.98 /
// R15 (this) 3.69 / R16 tagged 6.73 / R17 wave-autonomous 4.47 ms.
// ---------------------------------------------------------------------------
__global__ __launch_bounds__(256, 1) void scan_x_kernel(
    const float* __restrict__ init_h,
    const uint32_t* __restrict__ Wp16,   // [HID][K2]
    const float* __restrict__ pre,       // [T][B][HID]
    const float* __restrict__ tsp,       // [B][T]
    const float* __restrict__ Avec,
    const float* __restrict__ tau,
    uint32_t* __restrict__ hseq16,       // [T][B][256] f16 pairs
    uint32_t* __restrict__ hx,           // [2][B_SZ*K2] fragment-major
    uint32_t* __restrict__ flags,        // [NBLK][16]
    float* __restrict__ last_state)      // [B][HID]
{
  __shared__ uint32_t w_lds[JSL * WPAD];   // 66 KB

  const int bk   = blockIdx.x;
  const int tid  = threadIdx.x;
  const int wv   = tid >> 6;
  const int lane = tid & 63;
  const int qr   = wv >> 1;
  const int qc   = wv & 1;
  const int row16 = lane & 15;
  const int kg    = lane >> 4;

  const int j_loc  = qc * 16 + row16;
  const int j_glob = bk * JSL + j_loc;
  const int b0     = qr * 16 + kg * 4;

  {
    const uint32_t* src = Wp16 + (size_t)bk * JSL * K2;
    for (int i = tid; i < JSL * K2; i += 256)
      w_lds[(i >> 9) * WPAD + (i & (K2 - 1))] = src[i];
  }

  const float a_j  = Avec[j_glob];
  const float it_j = 1.f / tau[j_glob];
  float h_old[4];
  #pragma unroll
  for (int r = 0; r < 4; ++r) h_old[r] = init_h[(b0 + r) * HID + j_glob];

  float prevC[4], tsC[4];
  #pragma unroll
  for (int r = 0; r < 4; ++r) {
    prevC[r] = pre[(size_t)(b0 + r) * HID + j_glob];
    tsC[r]   = tsp[(b0 + r) * T_SZ + 0];
  }

  __syncthreads();

  const uint32_t* brow = &w_lds[j_loc * WPAD];
  const int ab2 = (qr * 16 + row16) * 2;            // u64 base within chunk
  const int pub_base = (j_glob >> 3) * 128 + ((j_glob >> 1) & 3);

  for (int t = 0; t < T_SZ; ++t) {
    if (t > 0) {
      if (tid < 64) {
        const uint32_t tgt = (uint32_t)t;
        while (__hip_atomic_load(&flags[(tid & 31) * 16],
                                 __ATOMIC_RELAXED, __HIP_MEMORY_SCOPE_AGENT) < tgt)
          __builtin_amdgcn_s_sleep(1);
      }
      __syncthreads();
    }

    // A fragments (coalesced coherent 8B loads)
    const unsigned long long* hxr =
        (const unsigned long long*)(hx + (t & 1) * (B_SZ * K2));
    unsigned long long a64[64];
    #pragma unroll
    for (int kk = 0; kk < 32; ++kk) {
      const size_t base = (size_t)(kk * 4 + kg) * 64 + ab2;
      a64[2 * kk]     = __hip_atomic_load(&hxr[base],
                          __ATOMIC_RELAXED, __HIP_MEMORY_SCOPE_AGENT);
      a64[2 * kk + 1] = __hip_atomic_load(&hxr[base + 1],
                          __ATOMIC_RELAXED, __HIP_MEMORY_SCOPE_AGENT);
    }

    f32x4 acc = {0.f, 0.f, 0.f, 0.f};
    #pragma unroll
    for (int kk = 0; kk < 32; ++kk) {
      const uint4 av = make_uint4((uint32_t)a64[2 * kk],
                                  (uint32_t)(a64[2 * kk] >> 32),
                                  (uint32_t)a64[2 * kk + 1],
                                  (uint32_t)(a64[2 * kk + 1] >> 32));
      const uint4 bv = *(const uint4*)(brow + kk * 16 + kg * 4);
      acc = __builtin_amdgcn_mfma_f32_16x16x32_f16(
          __builtin_bit_cast(f16x8, av), __builtin_bit_cast(f16x8, bv),
          acc, 0, 0, 0);
    }

    float hn[4];
    #pragma unroll
    for (int r = 0; r < 4; ++r) {
      const float z = acc[r] + prevC[r];
      const float f = 1.f / (1.f + __expf(-z));
      hn[r] = (h_old[r] + tsC[r] * f * a_j) / (1.f + tsC[r] * (it_j + f));
      h_old[r] = hn[r];
    }

    uint32_t pkv[4];
    #pragma unroll
    for (int r = 0; r < 4; ++r) {
      const float partner = __shfl_xor(hn[r], 1);
      pkv[r] = pk16(hn[r], partner);
    }

    // critical path: ONLY the hx publishes before the drain + flag
    uint32_t* hxw = hx + ((t + 1) & 1) * (B_SZ * K2);
    if ((row16 & 1) == 0) {
      #pragma unroll
      for (int r = 0; r < 4; ++r)
        __hip_atomic_store(&hxw[pub_base + (b0 + r) * 4], pkv[r],
                           __ATOMIC_RELAXED, __HIP_MEMORY_SCOPE_AGENT);
    }

    __syncthreads();   // drains the hx publishes (all 4 waves)

    if (tid == 0)
      __hip_atomic_store(&flags[bk * 16], (uint32_t)(t + 1),
                         __ATOMIC_RELAXED, __HIP_MEMORY_SCOPE_AGENT);

    // off-critical-path: hseq16 + next-step prefetch (finish under next poll)
    if (bk < 16 && (row16 & 1) == 0) {
      #pragma unroll
      for (int r = 0; r < 4; ++r)
        hseq16[(size_t)t * (B_SZ * 256) + (b0 + r) * 256 + (j_glob >> 1)] = pkv[r];
    }
    const int tn = (t + 1 < T_SZ) ? t + 1 : t;
    #pragma unroll
    for (int r = 0; r < 4; ++r) {
      prevC[r] = pre[(size_t)tn * (B_SZ * HID) + (b0 + r) * HID + j_glob];
      tsC[r]   = tsp[(b0 + r) * T_SZ + tn];
    }
  }

  #pragma unroll
  for (int r = 0; r < 4; ++r)
    last_state[(b0 + r) * HID + j_glob] = h_old[r];
}

extern "C" void kernel_launch(void* const* d_in, const int* in_sizes, int n_in,
                              void* d_out, int out_size, void* d_ws, size_t ws_size,
                              hipStream_t stream)
{
  const float* inputs    = (const float*)d_in[0];
  const float* timespans = (const float*)d_in[1];
  const float* init_h    = (const float*)d_in[2];
  const float* W_in      = (const float*)d_in[3];
  const float* b_in      = (const float*)d_in[4];
  const float* W_x       = (const float*)d_in[5];
  const float* W_h       = (const float*)d_in[6];
  const float* b_cell    = (const float*)d_in[7];
  const float* tau       = (const float*)d_in[8];
  const float* A         = (const float*)d_in[9];
  const float* W_out     = (const float*)d_in[10];
  const float* b_out     = (const float*)d_in[11];
  float* out = (float*)d_out;

  float*    ws     = (float*)d_ws;
  float*    pre    = ws;
  uint32_t* hseq16 = (uint32_t*)(pre + (size_t)T_SZ * B_SZ * HID);
  uint32_t* in16   = hseq16 + (size_t)T_SZ * B_SZ * 256;
  float*    Wxi    = (float*)(in16 + (size_t)B_SZ * T_SZ * 256);
  uint32_t* wxi16  = (uint32_t*)(Wxi + (size_t)HID * IN_SZ);
  uint32_t* wh16   = wxi16 + (size_t)HID * (IN_SZ / 2);
  uint32_t* wout16 = wh16 + (size_t)HID * K2;
  float*    beff   = (float*)(wout16 + (size_t)OUT_SZ * (MOT / 2));
  uint32_t* hx     = (uint32_t*)(beff + HID);
  uint32_t* flags  = hx + 2 * B_SZ * K2;                 // NBLK*16 u32

  // K0: Wxi = W_x @ W_in (f32)
  gemm_tiled<false><<<dim3(IN_SZ / 64, HID / 64), 256, 0, stream>>>(
      W_x, W_in, nullptr, Wxi, HID, IN_SZ, SEN, SEN,
      1 << 30, (long long)IN_SZ, 0LL);

  bias_eff_kernel<<<HID / 256, 256, 0, stream>>>(W_x, b_in, b_cell, beff);

  // packs
  pack16_kernel<<<(B_SZ * T_SZ * IN_SZ / 2) / 256, 256, 0, stream>>>(inputs, in16);
  pack16_kernel<<<(HID * IN_SZ / 2) / 256, 256, 0, stream>>>(Wxi, wxi16);
  pack16_kernel<<<(HID * HID / 2) / 256, 256, 0, stream>>>(W_h, wh16);
  pack16_kernel<<<(OUT_SZ * MOT / 2) / 256, 256, 0, stream>>>(W_out, wout16);

  // K1 (MFMA): pre = in16 @ wxi16^T + beff, scattered to [t][b][h]
  gemm_mfma<<<dim3(HID / 128, (B_SZ * T_SZ) / 128), 256, 0, stream>>>(
      in16, wxi16, beff, pre, IN_SZ / 2,
      T_SZ, (long long)B_SZ * HID, (long long)HID);

  // init exchange parity-0; zero flags
  init_hx_kernel<<<(B_SZ * K2) / 256, 256, 0, stream>>>(init_h, hx);
  (void)hipMemsetAsync(flags, 0, NBLK * 16 * sizeof(uint32_t), stream);

  // scan — 32 co-resident blocks (R15 protocol, measured optimum)
  {
    const uint32_t* wh16c = (const uint32_t*)wh16;
    float* last_state = out + (size_t)B_SZ * T_SZ * OUT_SZ;
    void* args[] = {
      (void*)&init_h, (void*)&wh16c, (void*)&pre, (void*)&timespans,
      (void*)&A, (void*)&tau, (void*)&hseq16, (void*)&hx, (void*)&flags,
      (void*)&last_state
    };
    (void)hipLaunchCooperativeKernel((void*)scan_x_kernel, dim3(NBLK), dim3(256),
                                     args, 0, stream);
  }

  // K3 (MFMA): out = hseq16 @ wout16^T + b_out, scattered to [b][t][o]
  gemm_mfma<<<dim3(OUT_SZ / 128, (B_SZ * T_SZ) / 128), 256, 0, stream>>>(
      hseq16, wout16, b_out, out, MOT / 2,
      B_SZ, (long long)T_SZ * OUT_SZ, (long long)OUT_SZ);
}